// Round 11
// baseline (790.687 us; speedup 1.0000x reference)
//
#include <hip/hip_runtime.h>
#include <hip/hip_cooperative_groups.h>

namespace cg = cooperative_groups;

#define NT 256

constexpr int R1c = 2048;
constexpr int R2c = 2624;
constexpr float EPSc = 1e-5f;

// ws float offsets (stats)
constexpr int SLOTS1  = 0;
constexpr int SLOTS1Q = 4096;
constexpr int SLOTS2  = 8192;
constexpr int SLOTS2Q = 12288;
constexpr int SLOTS3  = 16384;
constexpr int SLOTS3Q = 18432;
constexpr int FIN1    = 20480;
constexpr int FIN2    = 20608;
constexpr int FIN3    = 20736;
constexpr int STATS_ZERO_FLOATS = 20480;

// ws byte offsets
constexpr size_t ST2_OFF   = 131072;                   // bf16 transposed s
constexpr size_t ST2_BYTES = 8ull * 1024 * 4672 * 2;   // 76,546,048
constexpr size_t ZB_OFF    = ST2_OFF + ST2_BYTES;      // z bf16 [patch][64][64]
constexpr size_t ZB_BYTES  = 8192ull * 4096 * 2;       // 67,108,864
constexpr size_t Y_OFF     = ZB_OFF + ZB_BYTES;        // 143,785,984
constexpr size_t Y_BYTES   = 8192ull * 13312;          // y bf16 [patch][64][104]
constexpr size_t NEED_Y    = Y_OFF + Y_BYTES;          // 252,837,888
constexpr size_t OI_OFF    = Y_OFF;                    // o image overlays dead y

// ---- bf16 helpers -------------------------------------------------------
__device__ __forceinline__ ushort f_to_bf16(float f) {
    union { float f; unsigned int i; } v; v.f = f;
    unsigned int r = (v.i + 0x7fffu + ((v.i >> 16) & 1u)) >> 16;
    return (ushort)r;
}
__device__ __forceinline__ float bf16_to_f(ushort u) {
    union { unsigned int i; float f; } v; v.i = ((unsigned int)u) << 16; return v.f;
}
__device__ __forceinline__ float bf16lo_to_f(unsigned int u) {
    union { unsigned int i; float f; } v; v.i = u << 16; return v.f;
}
__device__ __forceinline__ float bf16hi_to_f(unsigned int u) {
    union { unsigned int i; float f; } v; v.i = u & 0xffff0000u; return v.f;
}
__device__ __forceinline__ unsigned int pack_bf16(float lo, float hi) {
    return (unsigned int)f_to_bf16(lo) | ((unsigned int)f_to_bf16(hi) << 16);
}

typedef short bf16x8 __attribute__((ext_vector_type(8)));
typedef float f32x4  __attribute__((ext_vector_type(4)));
union FR { uint4 u4; bf16x8 v; ushort s[8]; };

__device__ __forceinline__ f32x4 mfma16(bf16x8 a, bf16x8 b, f32x4 c) {
    return __builtin_amdgcn_mfma_f32_16x16x32_bf16(a, b, c, 0, 0, 0);
}

// ===========================================================================
// Shared phase bodies (verbatim R10 logic, parameterized by unit id)
// ===========================================================================

// transpose tile: tile id in [0, 18688) = bi*32*73 + qy*73 + px
__device__ __forceinline__ void dev_transpose(int tile, int t,
        const float* __restrict__ s, ushort* __restrict__ st, float* tl) {
    const int bi = tile / (73 * 32);
    int rem = tile - bi * 73 * 32;
    const int qy = rem / 73, px = rem - qy * 73;
    const int p0 = px * 64, q0 = qy * 32;
    const int tx = t & 31, ty = t >> 5;
    const float* sb = s + (size_t)bi * 4672 * 1024;
    #pragma unroll
    for (int r = ty; r < 64; r += 8)
        tl[r * 33 + tx] = sb[(size_t)(p0 + r) * 1024 + q0 + tx];
    __syncthreads();
    unsigned int* stu = (unsigned int*)(st + (size_t)bi * 1024 * 4672);
    #pragma unroll
    for (int rr = ty; rr < 32; rr += 8) {
        int q = q0 + rr;
        stu[((size_t)q * 4672 + p0) / 2 + tx] =
            pack_bf16(tl[(2 * tx) * 33 + rr], tl[(2 * tx + 1) * 33 + rr]);
    }
    __syncthreads();
}

// K1 unit in [0,4096): 2 patches, 2 waves/patch. frB = 2*3584 ushorts, st1 = 128 f.
__device__ __forceinline__ void dev_k1(int unit, int t,
        const float* __restrict__ x, const ushort* __restrict__ st2,
        ushort* __restrict__ ybuf, float* __restrict__ ws,
        ushort* frB, float* st1) {
    const int bi = unit >> 9, f = (unit >> 4) & 31, jb = unit & 15;
    const int g0 = jb * 2, slot = unit & 63;
    const int w = t >> 6, l = t & 63, l15 = l & 15, grp = l >> 4;
    const int pl_ = w >> 1, mh = w & 1;
    const int patch = bi * 1024 + f * 32 + g0 + pl_;

    if (t < 128) {
        st1[t] = 0.f;
        int p = t >> 6, e = t & 63;
        if ((e & 15) >= 4)
            ((uint4*)frB)[p * 448 + 384 + e] = make_uint4(0u, 0u, 0u, 0u);
    }
    const ushort* wp = st2 + (size_t)patch * 4672;
    FR aw[2];
    #pragma unroll
    for (int i = 0; i < 2; i++)
        aw[i].u4 = ((const uint4*)wp)[((mh * 2 + i) * 16 + l15) * 4 + grp];

    const float* xb = x + (size_t)bi * 32 * 65536;
    for (int i = t; i < 1920; i += NT) {
        int c = i / 60, rem = i - c * 60;
        int r = rem / 6, seg = rem - r * 6;
        int row = f * 8 - 1 + r; row = row < 0 ? -row : (row > 255 ? 510 - row : row);
        int col0 = g0 * 8 - 4 + seg * 4;
        float v4[4];
        if (col0 >= 0 && col0 <= 252) {
            float4 vv = *(const float4*)(xb + (size_t)c * 65536 + row * 256 + col0);
            v4[0] = vv.x; v4[1] = vv.y; v4[2] = vv.z; v4[3] = vv.w;
        } else {
            #pragma unroll
            for (int d = 0; d < 4; d++) {
                int cc = col0 + d; cc = cc < 0 ? -cc : (cc > 255 ? 510 - cc : cc);
                v4[d] = xb[(size_t)c * 65536 + row * 256 + cc];
            }
        }
        int grpc = c >> 3, j = c & 7;
        #pragma unroll
        for (int d = 0; d < 4; d++) {
            int u = col0 + d - g0 * 8;
            ushort hv = f_to_bf16(v4[d]);
            #pragma unroll
            for (int p = 0; p < 2; p++) {
                int pc = u - 8 * p + 1;
                if (pc >= 0 && pc <= 9) {
                    int px = r * 10 + pc;
                    frB[p * 3584 + ((px >> 4) * 64 + grpc * 16 + (px & 15)) * 8 + j] = hv;
                }
            }
        }
    }
    __syncthreads();

    FR b[7];
    const uint4* bp = (const uint4*)(frB + pl_ * 3584);
    #pragma unroll
    for (int n = 0; n < 7; n++) b[n].u4 = bp[n * 64 + l];
    __syncthreads();   // frag reads done -> overlay safe

    ushort* slice = frB + pl_ * 3584 + mh * 1792;
    unsigned int* sliceU = (unsigned int*)slice;
    uint4* yb4 = (uint4*)ybuf + (size_t)patch * 832;
    float s4[8], q4[8];
    #pragma unroll
    for (int i = 0; i < 8; i++) { s4[i] = 0.f; q4[i] = 0.f; }
    #pragma unroll
    for (int i = 0; i < 2; i++) {
        int mm = mh * 2 + i;
        #pragma unroll
        for (int n = 0; n < 7; n++) {
            f32x4 z = {0.f, 0.f, 0.f, 0.f};
            f32x4 c = mfma16(aw[i].v, b[n].v, z);
            int px = n * 16 + l15;
            #pragma unroll
            for (int r = 0; r < 4; r++) {
                float v = c[r]; s4[i*4+r] += v; q4[i*4+r] += v * v;
                if (px < 100) slice[(grp * 4 + r) * 106 + px] = f_to_bf16(v);
            }
        }
        for (int k = l; k < 208; k += 64) {
            int ch2 = k / 13, sub = k - ch2 * 13;
            int ub = ch2 * 53 + sub * 4;
            yb4[mm * 208 + k] = make_uint4(sliceU[ub], sliceU[ub+1], sliceU[ub+2], sliceU[ub+3]);
        }
    }
    #pragma unroll
    for (int i = 0; i < 8; i++) {
        float sm = s4[i], qq = q4[i];
        #pragma unroll
        for (int msk = 1; msk <= 8; msk <<= 1) { sm += __shfl_xor(sm, msk); qq += __shfl_xor(qq, msk); }
        if (l15 == 0) {
            int ch = (mh * 2 + (i >> 2)) * 16 + grp * 4 + (i & 3);
            atomicAdd(&st1[ch], sm);
            atomicAdd(&st1[64 + ch], qq);
        }
    }
    __syncthreads();
    if (t < 64) {
        atomicAdd(&ws[SLOTS1  + t * 64 + slot], st1[t]);
        atomicAdd(&ws[SLOTS1Q + t * 64 + slot], st1[64 + t]);
    }
    __syncthreads();
}

// K2 unit in [0,4096). slc = 4*1696 ushorts, w2L = 2*288 uints, fin = 128 f, acc = 128 f.
__device__ __forceinline__ void dev_k2(int unit, int t,
        const ushort* __restrict__ ybuf, const ushort* __restrict__ st2,
        ushort* __restrict__ zbuf, float* __restrict__ ws,
        ushort* slc, unsigned int* w2L, const float* fin, float* acc) {
    const int bi = unit >> 9, f = (unit >> 4) & 31, jb = unit & 15;
    const int g0 = jb * 2, slot = unit & 63;
    const int w = t >> 6, l = t & 63;
    const int pl_ = w >> 1, mh = w & 1;
    const int ch_l = l >> 2, quad = l & 3, p0 = quad * 2;
    const int patch = bi * 1024 + f * 32 + g0 + pl_;

    if (t < 128) acc[t] = 0.f;
    for (int k = t; k < 576; k += NT) {
        int p = (k >= 288) ? 1 : 0;
        int kk = k - p * 288;
        const unsigned int* src = (const unsigned int*)(st2 + (size_t)(bi*1024 + f*32 + g0 + p) * 4672 + R1c);
        w2L[k] = src[kk];
    }
    __syncthreads();

    const uint4* yb4 = (const uint4*)ybuf + (size_t)patch * 832;
    ushort* slice = slc + w * 1696;
    unsigned int* sliceU = (unsigned int*)slice;
    const ushort* w2u = (const ushort*)(w2L + pl_ * 288);
    ushort* zp0 = zbuf + (size_t)patch * 4096;

    #pragma unroll
    for (int i = 0; i < 2; i++) {
        int mm = mh * 2 + i;
        for (int k = l; k < 208; k += 64) {
            uint4 v = yb4[mm * 208 + k];
            int ch2 = k / 13, sub = k - ch2 * 13;
            int ch = mm * 16 + ch2;
            float a1 = fin[ch], b1 = fin[64 + ch];
            unsigned int uu[4] = {v.x, v.y, v.z, v.w};
            int ub = ch2 * 53 + sub * 4;
            #pragma unroll
            for (int kk = 0; kk < 4; kk++) {
                float lo = fminf(fmaxf(bf16lo_to_f(uu[kk]) * a1 + b1, 0.f), 6.f);
                float hi = fminf(fmaxf(bf16hi_to_f(uu[kk]) * a1 + b1, 0.f), 6.f);
                sliceU[ub + kk] = pack_bf16(lo, hi);
            }
        }
        float yv[4][10];
        #pragma unroll
        for (int rr = 0; rr < 4; rr++) {
            int base = ch_l * 53 + (p0 + rr) * 5;
            #pragma unroll
            for (int k = 0; k < 5; k++) {
                unsigned int u = sliceU[base + k];
                yv[rr][2*k] = bf16lo_to_f(u); yv[rr][2*k+1] = bf16hi_to_f(u);
            }
        }
        float wt[9];
        #pragma unroll
        for (int k = 0; k < 9; k++) wt[k] = bf16_to_f(w2u[(mm * 16 + ch_l) * 9 + k]);
        float za[2][8];
        #pragma unroll
        for (int rr = 0; rr < 2; rr++)
            #pragma unroll
            for (int q = 0; q < 8; q++) za[rr][q] = 0.f;
        #pragma unroll
        for (int u = 0; u < 3; u++)
            #pragma unroll
            for (int v = 0; v < 3; v++) {
                float wv = wt[u * 3 + v];
                #pragma unroll
                for (int rr = 0; rr < 2; rr++)
                    #pragma unroll
                    for (int q = 0; q < 8; q++)
                        za[rr][q] += wv * yv[rr + u][q + v];
            }
        float zs = 0.f, zq = 0.f;
        #pragma unroll
        for (int rr = 0; rr < 2; rr++)
            #pragma unroll
            for (int q = 0; q < 8; q++) { float v = za[rr][q]; zs += v; zq += v * v; }
        zs += __shfl_xor(zs, 1); zs += __shfl_xor(zs, 2);
        zq += __shfl_xor(zq, 1); zq += __shfl_xor(zq, 2);
        if (quad == 0) {
            atomicAdd(&acc[mm * 16 + ch_l], zs);
            atomicAdd(&acc[64 + mm * 16 + ch_l], zq);
        }
        ushort* zp = zp0 + (mm * 16 + ch_l) * 64 + p0 * 8;
        uint4 pk0, pk1;
        pk0.x = pack_bf16(za[0][0], za[0][1]); pk0.y = pack_bf16(za[0][2], za[0][3]);
        pk0.z = pack_bf16(za[0][4], za[0][5]); pk0.w = pack_bf16(za[0][6], za[0][7]);
        pk1.x = pack_bf16(za[1][0], za[1][1]); pk1.y = pack_bf16(za[1][2], za[1][3]);
        pk1.z = pack_bf16(za[1][4], za[1][5]); pk1.w = pack_bf16(za[1][6], za[1][7]);
        *(uint4*)zp = pk0;
        *(uint4*)(zp + 8) = pk1;
    }
    __syncthreads();
    if (t < 64) {
        atomicAdd(&ws[SLOTS2  + t * 64 + slot], acc[t]);
        atomicAdd(&ws[SLOTS2Q + t * 64 + slot], acc[64 + t]);
    }
    __syncthreads();
}

// K3 unit in [0,4096). zL = 2*4224 ushorts, fin = 128 f, acc >= 64 f.
__device__ __forceinline__ void dev_k3(int unit, int t,
        const ushort* __restrict__ zbuf, const ushort* __restrict__ st2,
        ushort* __restrict__ oi, float* __restrict__ ws,
        ushort* zL, const float* fin, float* acc) {
    const int bi = unit >> 9, f = (unit >> 4) & 31, jb = unit & 15;
    const int g0 = jb * 2, slot = unit & 63;
    const int w = t >> 6, l = t & 63, l15 = l & 15, grp = l >> 4;
    const int pl_ = w >> 1, mh = w & 1;
    const int patch = bi * 1024 + f * 32 + g0 + pl_;

    if (t < 64) acc[t] = 0.f;
    const ushort* wp = st2 + (size_t)patch * 4672;
    FR aw[2];
    #pragma unroll
    for (int ks = 0; ks < 2; ks++)
        aw[ks].u4 = ((const uint4*)(wp + R2c))[(mh * 16 + l15) * 8 + ks * 4 + grp];

    const uint4* zsrc = (const uint4*)(zbuf + (size_t)patch * 4096);
    unsigned int* zd = (unsigned int*)zL;
    #pragma unroll
    for (int it = 0; it < 4; it++) {
        int i = mh * 256 + it * 64 + l;
        uint4 v = zsrc[i];
        int ch = i >> 3, px0 = (i & 7) * 8;
        float a2 = fin[ch], b2 = fin[64 + ch];
        unsigned int uu[4] = {v.x, v.y, v.z, v.w};
        int base = pl_ * 2112 + (ch * 66 + px0) / 2;
        #pragma unroll
        for (int k = 0; k < 4; k++) {
            float lo = fminf(fmaxf(bf16lo_to_f(uu[k]) * a2 + b2, 0.f), 6.f);
            float hi = fminf(fmaxf(bf16hi_to_f(uu[k]) * a2 + b2, 0.f), 6.f);
            zd[base + k] = pack_bf16(lo, hi);
        }
    }
    __syncthreads();

    FR bfr[2][4];
    #pragma unroll
    for (int ks = 0; ks < 2; ks++)
        #pragma unroll
        for (int n = 0; n < 4; n++)
            #pragma unroll
            for (int j = 0; j < 8; j++)
                bfr[ks][n].s[j] = zL[pl_ * 4224 + (ks * 32 + grp * 8 + j) * 66 + n * 16 + l15];

    float s4[4], q4[4];
    #pragma unroll
    for (int r = 0; r < 4; r++) { s4[r] = 0.f; q4[r] = 0.f; }
    #pragma unroll
    for (int n = 0; n < 4; n++) {
        f32x4 z = {0.f, 0.f, 0.f, 0.f};
        f32x4 c = mfma16(aw[0].v, bfr[0][n].v, z);
        c = mfma16(aw[1].v, bfr[1][n].v, c);
        #pragma unroll
        for (int r = 0; r < 4; r++) {
            float v = c[r];
            s4[r] += v; q4[r] += v * v;
            int oc = mh * 16 + grp * 4 + r;
            int px = n * 16 + l15, p = px >> 3, q = px & 7;
            oi[((size_t)(bi * 32 + oc) * 256 + f * 8 + p) * 256 + (g0 + pl_) * 8 + q] = f_to_bf16(v);
        }
    }
    #pragma unroll
    for (int r = 0; r < 4; r++) {
        float sm = s4[r], qq = q4[r];
        #pragma unroll
        for (int msk = 1; msk <= 8; msk <<= 1) { sm += __shfl_xor(sm, msk); qq += __shfl_xor(qq, msk); }
        if (l15 == 0) {
            int oc = mh * 16 + grp * 4 + r;
            atomicAdd(&acc[oc], sm);
            atomicAdd(&acc[32 + oc], qq);
        }
    }
    __syncthreads();
    if (t < 32) {
        atomicAdd(&ws[SLOTS3  + t * 64 + slot], acc[t]);
        atomicAdd(&ws[SLOTS3Q + t * 64 + slot], acc[32 + t]);
    }
    __syncthreads();
}

// K4 chunk: 256 float4 per call starting at float4-index base.
__device__ __forceinline__ void dev_k4(size_t base, int t,
        const float* __restrict__ x, const ushort* __restrict__ oi,
        float* __restrict__ out, const float* fin3) {
    size_t e = (base + t) * 4;
    int oc = (int)((e >> 16) & 31);
    float a3 = fin3[oc], b3 = fin3[32 + oc];
    uint2 ov = *(const uint2*)(oi + e);
    float4 xv = *(const float4*)(x + e);
    float4 r;
    r.x = xv.x + bf16lo_to_f(ov.x) * a3 + b3;
    r.y = xv.y + bf16hi_to_f(ov.x) * a3 + b3;
    r.z = xv.z + bf16lo_to_f(ov.y) * a3 + b3;
    r.w = xv.w + bf16hi_to_f(ov.y) * a3 + b3;
    *(float4*)(out + e) = r;
}

// per-block finalize: reduce slots -> a,b into finL.
__device__ __forceinline__ void dev_fin(const float* __restrict__ ws, int so, int sq,
        const float* __restrict__ gamma, const float* __restrict__ beta,
        int nch, float N, float* finL, int t) {
    if (t < nch) {
        float sm = 0.f, qq = 0.f;
        for (int j = 0; j < 64; j++) { sm += ws[so + t*64 + j]; qq += ws[sq + t*64 + j]; }
        float mean = sm / N;
        float var  = qq / N - mean * mean;
        float a = rsqrtf(var + EPSc) * gamma[t];
        finL[t]       = a;
        finL[nch + t] = beta[t] - mean * a;
    }
    __syncthreads();
}

// ===========================================================================
// Cooperative fused kernel: 1024 blocks x 256 threads (4 blocks/CU).
// ===========================================================================
__global__ __launch_bounds__(NT, 4)
void fused_coop(const float* __restrict__ x, const float* __restrict__ s,
                ushort* st2, ushort* ybuf, ushort* zbuf, ushort* oi,
                float* ws,
                const float* g1, const float* b1, const float* g2, const float* b2,
                const float* g3, const float* b3, float* out) {
    __shared__ __align__(16) char region[16896];
    __shared__ float finL[128];
    __shared__ float accL[128];
    const int t = threadIdx.x, blk = blockIdx.x;
    cg::grid_group grid = cg::this_grid();

    // phase 0: zero stats slots + transpose s -> st2
    {
        int idx = blk * NT + t;
        if (idx < STATS_ZERO_FLOATS) ws[idx] = 0.f;
        float* tl = (float*)region;
        for (int tile = blk; tile < 18688; tile += 1024)
            dev_transpose(tile, t, s, st2, tl);
    }
    grid.sync();

    // phase 1: stage-1 MFMA + stats1 + y store
    for (int u = blk; u < 4096; u += 1024)
        dev_k1(u, t, x, st2, ybuf, ws, (ushort*)region, accL);
    grid.sync();

    // phase 2: BN1 finalize (per-block) + depthwise + stats2 + z store
    dev_fin(ws, SLOTS1, SLOTS1Q, g1, b1, 64, 819200.0f, finL, t);
    for (int u = blk; u < 4096; u += 1024)
        dev_k2(u, t, ybuf, st2, zbuf, ws, (ushort*)region,
               (unsigned int*)(region + 13568), finL, accL);
    grid.sync();

    // phase 3: BN2 finalize + stage-3 MFMA + stats3 + o image store
    dev_fin(ws, SLOTS2, SLOTS2Q, g2, b2, 64, 524288.0f, finL, t);
    for (int u = blk; u < 4096; u += 1024)
        dev_k3(u, t, zbuf, st2, oi, ws, (ushort*)region, finL, accL);
    grid.sync();

    // phase 4: BN3 finalize + residual stream-out
    dev_fin(ws, SLOTS3, SLOTS3Q, g3, b3, 32, 524288.0f, finL, t);
    #pragma unroll
    for (int it = 0; it < 16; it++)
        dev_k4((size_t)(it * 1024 + blk) * 256, t, x, oi, out, finL);
}

// ===========================================================================
// Fallback: R10 multi-kernel path via thin wrappers over the same dev bodies.
// ===========================================================================
__global__ __launch_bounds__(256)
void transpose_w(const float* __restrict__ s, ushort* __restrict__ st) {
    __shared__ float tl[2112];
    dev_transpose(blockIdx.x, threadIdx.x, s, st, tl);
}

__global__ __launch_bounds__(NT, 2)
void k1_w(const float* __restrict__ x, const ushort* __restrict__ st2,
          ushort* __restrict__ yb, float* __restrict__ ws) {
    __shared__ __align__(16) ushort frB[2 * 3584];
    __shared__ float st1[128];
    dev_k1(blockIdx.x, threadIdx.x, x, st2, yb, ws, frB, st1);
}

__global__ __launch_bounds__(NT, 2)
void k2_w(const ushort* __restrict__ yb, const ushort* __restrict__ st2,
          ushort* __restrict__ zb, float* __restrict__ ws) {
    __shared__ __align__(16) ushort slc[4 * 1696];
    __shared__ unsigned int w2L[2 * 288];
    __shared__ float finL[128];
    __shared__ float accL[128];
    if (threadIdx.x < 128) finL[threadIdx.x] = ws[FIN1 + threadIdx.x];
    __syncthreads();
    dev_k2(blockIdx.x, threadIdx.x, yb, st2, zb, ws, slc, w2L, finL, accL);
}

__global__ __launch_bounds__(NT, 2)
void k3_w(const ushort* __restrict__ zb, const ushort* __restrict__ st2,
          ushort* __restrict__ oi, float* __restrict__ ws) {
    __shared__ __align__(16) ushort zL[2 * 4224];
    __shared__ float finL[128];
    __shared__ float accL[64];
    if (threadIdx.x < 128) finL[threadIdx.x] = ws[FIN2 + threadIdx.x];
    __syncthreads();
    dev_k3(blockIdx.x, threadIdx.x, zb, st2, oi, ws, zL, finL, accL);
}

__global__ __launch_bounds__(NT, 8)
void k4_w(const float* __restrict__ x, const float* __restrict__ ws,
          const ushort* __restrict__ oi, float* __restrict__ out) {
    __shared__ float finL[64];
    if (threadIdx.x < 64) finL[threadIdx.x] = ws[FIN3 + threadIdx.x];
    __syncthreads();
    #pragma unroll
    for (int it = 0; it < 8; it++)
        dev_k4((size_t)(it * 2048 + blockIdx.x) * 256, threadIdx.x, x, oi, out, finL);
}

__global__ void finalize_k(float* __restrict__ ws, int stage,
                           const float* __restrict__ gamma, const float* __restrict__ beta) {
    int ch = threadIdx.x;
    int nch = (stage == 3) ? 32 : 64;
    if (ch >= nch) return;
    int so = (stage == 1) ? SLOTS1  : (stage == 2) ? SLOTS2  : SLOTS3;
    int sq = (stage == 1) ? SLOTS1Q : (stage == 2) ? SLOTS2Q : SLOTS3Q;
    int fo = (stage == 1) ? FIN1    : (stage == 2) ? FIN2    : FIN3;
    float N = (stage == 1) ? 819200.0f : 524288.0f;
    float sm = 0.f, qq = 0.f;
    for (int j = 0; j < 64; j++) { sm += ws[so + ch*64 + j]; qq += ws[sq + ch*64 + j]; }
    float mean = sm / N;
    float var  = qq / N - mean * mean;
    float rstd = rsqrtf(var + EPSc);
    float a = rstd * gamma[ch];
    ws[fo + ch]       = a;
    ws[fo + nch + ch] = beta[ch] - mean * a;
}

// ---------------------------------------------------------------------------
extern "C" void kernel_launch(void* const* d_in, const int* in_sizes, int n_in,
                              void* d_out, int out_size, void* d_ws, size_t ws_size,
                              hipStream_t stream) {
    const float* x  = (const float*)d_in[0];
    const float* s  = (const float*)d_in[1];
    const float* g1 = (const float*)d_in[2];
    const float* b1 = (const float*)d_in[3];
    const float* g2 = (const float*)d_in[4];
    const float* b2 = (const float*)d_in[5];
    const float* g3 = (const float*)d_in[6];
    const float* b3 = (const float*)d_in[7];
    float* out = (float*)d_out;
    float* ws  = (float*)d_ws;

    ushort* st2 = (ushort*)((char*)d_ws + ST2_OFF);
    ushort* zb  = (ushort*)((char*)d_ws + ZB_OFF);
    ushort* yb  = (ushort*)((char*)d_ws + Y_OFF);
    ushort* oi  = (ushort*)((char*)d_ws + OI_OFF);

    if (ws_size >= NEED_Y) {
        void* kargs[] = {
            (void*)&x, (void*)&s, (void*)&st2, (void*)&yb, (void*)&zb, (void*)&oi,
            (void*)&ws, (void*)&g1, (void*)&b1, (void*)&g2, (void*)&b2,
            (void*)&g3, (void*)&b3, (void*)&out
        };
        hipError_t err = hipLaunchCooperativeKernel((void*)fused_coop,
                                                    dim3(1024), dim3(NT),
                                                    kargs, 0, stream);
        if (err == hipSuccess) return;
    }

    // fallback: R10 multi-kernel path
    hipMemsetAsync(d_ws, 0, STATS_ZERO_FLOATS * sizeof(float), stream);
    transpose_w<<<18688, 256, 0, stream>>>(s, st2);
    k1_w<<<4096, NT, 0, stream>>>(x, st2, yb, ws);
    finalize_k<<<1, 64, 0, stream>>>(ws, 1, g1, b1);
    k2_w<<<4096, NT, 0, stream>>>(yb, st2, zb, ws);
    finalize_k<<<1, 64, 0, stream>>>(ws, 2, g2, b2);
    k3_w<<<4096, NT, 0, stream>>>(zb, st2, oi, ws);
    finalize_k<<<1, 64, 0, stream>>>(ws, 3, g3, b3);
    k4_w<<<2048, NT, 0, stream>>>(x, ws, oi, out);
}

// Round 12
// 288.204 us; speedup vs baseline: 2.7435x; 2.7435x over previous
//
#include <hip/hip_runtime.h>

#define NT 256

constexpr int R1c = 2048;
constexpr int R2c = 2624;
constexpr float EPSc = 1e-5f;

// ws float offsets (stats)
constexpr int SLOTS1  = 0;
constexpr int SLOTS1Q = 4096;
constexpr int SLOTS2  = 8192;
constexpr int SLOTS2Q = 12288;
constexpr int SLOTS3  = 16384;
constexpr int SLOTS3Q = 18432;
constexpr int STATS_ZERO_FLOATS = 20480;

// ws byte offsets
constexpr size_t ST2_OFF   = 131072;                   // bf16 transposed s
constexpr size_t ST2_BYTES = 8ull * 1024 * 4672 * 2;   // 76,546,048
constexpr size_t ZB_OFF    = ST2_OFF + ST2_BYTES;      // z bf16 [patch][64][64]
constexpr size_t ZB_BYTES  = 8192ull * 4096 * 2;       // 67,108,864
constexpr size_t Y_OFF     = ZB_OFF + ZB_BYTES;        // 143,785,984
constexpr size_t Y_BYTES   = 8192ull * 13312;          // y bf16 [patch][64][104]
constexpr size_t NEED_Y    = Y_OFF + Y_BYTES;          // 252,837,888
constexpr size_t OI_OFF    = Y_OFF;                    // o image overlays dead y

// ---- bf16 helpers -------------------------------------------------------
__device__ __forceinline__ ushort f_to_bf16(float f) {
    union { float f; unsigned int i; } v; v.f = f;
    unsigned int r = (v.i + 0x7fffu + ((v.i >> 16) & 1u)) >> 16;
    return (ushort)r;
}
__device__ __forceinline__ float bf16_to_f(ushort u) {
    union { unsigned int i; float f; } v; v.i = ((unsigned int)u) << 16; return v.f;
}
__device__ __forceinline__ float bf16lo_to_f(unsigned int u) {
    union { unsigned int i; float f; } v; v.i = u << 16; return v.f;
}
__device__ __forceinline__ float bf16hi_to_f(unsigned int u) {
    union { unsigned int i; float f; } v; v.i = u & 0xffff0000u; return v.f;
}
__device__ __forceinline__ unsigned int pack_bf16(float lo, float hi) {
    return (unsigned int)f_to_bf16(lo) | ((unsigned int)f_to_bf16(hi) << 16);
}

typedef short bf16x8 __attribute__((ext_vector_type(8)));
typedef float f32x4  __attribute__((ext_vector_type(4)));
union FR { uint4 u4; bf16x8 v; ushort s[8]; };

__device__ __forceinline__ f32x4 mfma16(bf16x8 a, bf16x8 b, f32x4 c) {
    return __builtin_amdgcn_mfma_f32_16x16x32_bf16(a, b, c, 0, 0, 0);
}

// per-block finalize from slots: finL[ch]=a, finL[nch+ch]=b.
__device__ __forceinline__ void dev_fin(const float* __restrict__ ws, int so, int sq,
        const float* __restrict__ gamma, const float* __restrict__ beta,
        int nch, float N, float* finL, int t) {
    if (t < nch) {
        float sm = 0.f, qq = 0.f;
        for (int j = 0; j < 64; j++) { sm += ws[so + t*64 + j]; qq += ws[sq + t*64 + j]; }
        float mean = sm / N;
        float var  = qq / N - mean * mean;
        float a = rsqrtf(var + EPSc) * gamma[t];
        finL[t]       = a;
        finL[nch + t] = beta[t] - mean * a;
    }
    __syncthreads();
}

// ---------------------------------------------------------------------------
// Transpose s -> st2 bf16; also zeroes the stats slot region (blocks 0..79).
__global__ __launch_bounds__(256)
void transpose_w(const float* __restrict__ s, ushort* __restrict__ st,
                 float* __restrict__ ws) {
    __shared__ float tl[2112];
    const int tile = blockIdx.x, t = threadIdx.x;
    if (tile < 80) {
        int idx = tile * 256 + t;
        if (idx < STATS_ZERO_FLOATS) ws[idx] = 0.f;
    }
    const int bi = tile / (73 * 32);
    int rem = tile - bi * 73 * 32;
    const int qy = rem / 73, px = rem - qy * 73;
    const int p0 = px * 64, q0 = qy * 32;
    const int tx = t & 31, ty = t >> 5;
    const float* sb = s + (size_t)bi * 4672 * 1024;
    #pragma unroll
    for (int r = ty; r < 64; r += 8)
        tl[r * 33 + tx] = sb[(size_t)(p0 + r) * 1024 + q0 + tx];
    __syncthreads();
    unsigned int* stu = (unsigned int*)(st + (size_t)bi * 1024 * 4672);
    #pragma unroll
    for (int rr = ty; rr < 32; rr += 8) {
        int q = q0 + rr;
        stu[((size_t)q * 4672 + p0) / 2 + tx] =
            pack_bf16(tl[(2 * tx) * 33 + rr], tl[(2 * tx + 1) * 33 + rr]);
    }
}

// ---------------------------------------------------------------------------
// K1: 2 patches/block, 2 waves/patch. Stage-1 MFMA + stats1 + y store.
__global__ __launch_bounds__(NT, 4)
void k1_w(const float* __restrict__ x, const ushort* __restrict__ st2,
          ushort* __restrict__ ybuf, float* __restrict__ ws) {
    __shared__ __align__(16) ushort frB[2 * 3584];
    __shared__ float st1[128];
    const int t = threadIdx.x, unit = blockIdx.x;
    const int bi = unit >> 9, f = (unit >> 4) & 31, jb = unit & 15;
    const int g0 = jb * 2, slot = unit & 63;
    const int w = t >> 6, l = t & 63, l15 = l & 15, grp = l >> 4;
    const int pl_ = w >> 1, mh = w & 1;
    const int patch = bi * 1024 + f * 32 + g0 + pl_;

    if (t < 128) {
        st1[t] = 0.f;
        int p = t >> 6, e = t & 63;
        if ((e & 15) >= 4)
            ((uint4*)frB)[p * 448 + 384 + e] = make_uint4(0u, 0u, 0u, 0u);
    }
    const ushort* wp = st2 + (size_t)patch * 4672;
    FR aw[2];
    #pragma unroll
    for (int i = 0; i < 2; i++)
        aw[i].u4 = ((const uint4*)wp)[((mh * 2 + i) * 16 + l15) * 4 + grp];

    const float* xb = x + (size_t)bi * 32 * 65536;
    for (int i = t; i < 1920; i += NT) {
        int c = i / 60, rem = i - c * 60;
        int r = rem / 6, seg = rem - r * 6;
        int row = f * 8 - 1 + r; row = row < 0 ? -row : (row > 255 ? 510 - row : row);
        int col0 = g0 * 8 - 4 + seg * 4;
        float v4[4];
        if (col0 >= 0 && col0 <= 252) {
            float4 vv = *(const float4*)(xb + (size_t)c * 65536 + row * 256 + col0);
            v4[0] = vv.x; v4[1] = vv.y; v4[2] = vv.z; v4[3] = vv.w;
        } else {
            #pragma unroll
            for (int d = 0; d < 4; d++) {
                int cc = col0 + d; cc = cc < 0 ? -cc : (cc > 255 ? 510 - cc : cc);
                v4[d] = xb[(size_t)c * 65536 + row * 256 + cc];
            }
        }
        int grpc = c >> 3, j = c & 7;
        #pragma unroll
        for (int d = 0; d < 4; d++) {
            int u = col0 + d - g0 * 8;
            ushort hv = f_to_bf16(v4[d]);
            #pragma unroll
            for (int p = 0; p < 2; p++) {
                int pc = u - 8 * p + 1;
                if (pc >= 0 && pc <= 9) {
                    int px = r * 10 + pc;
                    frB[p * 3584 + ((px >> 4) * 64 + grpc * 16 + (px & 15)) * 8 + j] = hv;
                }
            }
        }
    }
    __syncthreads();

    FR b[7];
    const uint4* bp = (const uint4*)(frB + pl_ * 3584);
    #pragma unroll
    for (int n = 0; n < 7; n++) b[n].u4 = bp[n * 64 + l];
    __syncthreads();   // frag reads done -> overlay safe

    ushort* slice = frB + pl_ * 3584 + mh * 1792;
    unsigned int* sliceU = (unsigned int*)slice;
    uint4* yb4 = (uint4*)ybuf + (size_t)patch * 832;
    float s4[8], q4[8];
    #pragma unroll
    for (int i = 0; i < 8; i++) { s4[i] = 0.f; q4[i] = 0.f; }
    #pragma unroll
    for (int i = 0; i < 2; i++) {
        int mm = mh * 2 + i;
        #pragma unroll
        for (int n = 0; n < 7; n++) {
            f32x4 z = {0.f, 0.f, 0.f, 0.f};
            f32x4 c = mfma16(aw[i].v, b[n].v, z);
            int px = n * 16 + l15;
            #pragma unroll
            for (int r = 0; r < 4; r++) {
                float v = c[r]; s4[i*4+r] += v; q4[i*4+r] += v * v;
                if (px < 100) slice[(grp * 4 + r) * 106 + px] = f_to_bf16(v);
            }
        }
        for (int k = l; k < 208; k += 64) {
            int ch2 = k / 13, sub = k - ch2 * 13;
            int ub = ch2 * 53 + sub * 4;
            yb4[mm * 208 + k] = make_uint4(sliceU[ub], sliceU[ub+1], sliceU[ub+2], sliceU[ub+3]);
        }
    }
    #pragma unroll
    for (int i = 0; i < 8; i++) {
        float sm = s4[i], qq = q4[i];
        #pragma unroll
        for (int msk = 1; msk <= 8; msk <<= 1) { sm += __shfl_xor(sm, msk); qq += __shfl_xor(qq, msk); }
        if (l15 == 0) {
            int ch = (mh * 2 + (i >> 2)) * 16 + grp * 4 + (i & 3);
            atomicAdd(&st1[ch], sm);
            atomicAdd(&st1[64 + ch], qq);
        }
    }
    __syncthreads();
    if (t < 64) {
        atomicAdd(&ws[SLOTS1  + t * 64 + slot], st1[t]);
        atomicAdd(&ws[SLOTS1Q + t * 64 + slot], st1[64 + t]);
    }
}

// ---------------------------------------------------------------------------
// K2: per-block BN1 finalize from slots; y read -> BN1+relu6 -> depthwise ->
//     stats2 -> z store.
__global__ __launch_bounds__(NT, 4)
void k2_w(const ushort* __restrict__ ybuf, const ushort* __restrict__ st2,
          ushort* __restrict__ zbuf, float* __restrict__ ws,
          const float* __restrict__ g1, const float* __restrict__ b1) {
    __shared__ __align__(16) ushort slc[4 * 1696];
    __shared__ unsigned int w2L[2 * 288];
    __shared__ float finL[128];
    __shared__ float accL[128];
    const int t = threadIdx.x, unit = blockIdx.x;
    const int bi = unit >> 9, f = (unit >> 4) & 31, jb = unit & 15;
    const int g0 = jb * 2, slot = unit & 63;
    const int w = t >> 6, l = t & 63;
    const int pl_ = w >> 1, mh = w & 1;
    const int ch_l = l >> 2, quad = l & 3, p0 = quad * 2;
    const int patch = bi * 1024 + f * 32 + g0 + pl_;

    dev_fin(ws, SLOTS1, SLOTS1Q, g1, b1, 64, 819200.0f, finL, t);
    if (t < 128) accL[t] = 0.f;
    for (int k = t; k < 576; k += NT) {
        int p = (k >= 288) ? 1 : 0;
        int kk = k - p * 288;
        const unsigned int* src = (const unsigned int*)(st2 + (size_t)(bi*1024 + f*32 + g0 + p) * 4672 + R1c);
        w2L[k] = src[kk];
    }
    __syncthreads();

    const uint4* yb4 = (const uint4*)ybuf + (size_t)patch * 832;
    ushort* slice = slc + w * 1696;
    unsigned int* sliceU = (unsigned int*)slice;
    const ushort* w2u = (const ushort*)(w2L + pl_ * 288);
    ushort* zp0 = zbuf + (size_t)patch * 4096;

    #pragma unroll
    for (int i = 0; i < 2; i++) {
        int mm = mh * 2 + i;
        for (int k = l; k < 208; k += 64) {
            uint4 v = yb4[mm * 208 + k];
            int ch2 = k / 13, sub = k - ch2 * 13;
            int ch = mm * 16 + ch2;
            float a1 = finL[ch], bb1 = finL[64 + ch];
            unsigned int uu[4] = {v.x, v.y, v.z, v.w};
            int ub = ch2 * 53 + sub * 4;
            #pragma unroll
            for (int kk = 0; kk < 4; kk++) {
                float lo = fminf(fmaxf(bf16lo_to_f(uu[kk]) * a1 + bb1, 0.f), 6.f);
                float hi = fminf(fmaxf(bf16hi_to_f(uu[kk]) * a1 + bb1, 0.f), 6.f);
                sliceU[ub + kk] = pack_bf16(lo, hi);
            }
        }
        float yv[4][10];
        #pragma unroll
        for (int rr = 0; rr < 4; rr++) {
            int base = ch_l * 53 + (p0 + rr) * 5;
            #pragma unroll
            for (int k = 0; k < 5; k++) {
                unsigned int u = sliceU[base + k];
                yv[rr][2*k] = bf16lo_to_f(u); yv[rr][2*k+1] = bf16hi_to_f(u);
            }
        }
        float wt[9];
        #pragma unroll
        for (int k = 0; k < 9; k++) wt[k] = bf16_to_f(w2u[(mm * 16 + ch_l) * 9 + k]);
        float za[2][8];
        #pragma unroll
        for (int rr = 0; rr < 2; rr++)
            #pragma unroll
            for (int q = 0; q < 8; q++) za[rr][q] = 0.f;
        #pragma unroll
        for (int u = 0; u < 3; u++)
            #pragma unroll
            for (int v = 0; v < 3; v++) {
                float wv = wt[u * 3 + v];
                #pragma unroll
                for (int rr = 0; rr < 2; rr++)
                    #pragma unroll
                    for (int q = 0; q < 8; q++)
                        za[rr][q] += wv * yv[rr + u][q + v];
            }
        float zs = 0.f, zq = 0.f;
        #pragma unroll
        for (int rr = 0; rr < 2; rr++)
            #pragma unroll
            for (int q = 0; q < 8; q++) { float v = za[rr][q]; zs += v; zq += v * v; }
        zs += __shfl_xor(zs, 1); zs += __shfl_xor(zs, 2);
        zq += __shfl_xor(zq, 1); zq += __shfl_xor(zq, 2);
        if (quad == 0) {
            atomicAdd(&accL[mm * 16 + ch_l], zs);
            atomicAdd(&accL[64 + mm * 16 + ch_l], zq);
        }
        ushort* zp = zp0 + (mm * 16 + ch_l) * 64 + p0 * 8;
        uint4 pk0, pk1;
        pk0.x = pack_bf16(za[0][0], za[0][1]); pk0.y = pack_bf16(za[0][2], za[0][3]);
        pk0.z = pack_bf16(za[0][4], za[0][5]); pk0.w = pack_bf16(za[0][6], za[0][7]);
        pk1.x = pack_bf16(za[1][0], za[1][1]); pk1.y = pack_bf16(za[1][2], za[1][3]);
        pk1.z = pack_bf16(za[1][4], za[1][5]); pk1.w = pack_bf16(za[1][6], za[1][7]);
        *(uint4*)zp = pk0;
        *(uint4*)(zp + 8) = pk1;
    }
    __syncthreads();
    if (t < 64) {
        atomicAdd(&ws[SLOTS2  + t * 64 + slot], accL[t]);
        atomicAdd(&ws[SLOTS2Q + t * 64 + slot], accL[64 + t]);
    }
}

// ---------------------------------------------------------------------------
// K3: per-block BN2 finalize; z -> BN2+relu6 -> MFMA -> stats3 + o image.
__global__ __launch_bounds__(NT, 4)
void k3_w(const ushort* __restrict__ zbuf, const ushort* __restrict__ st2,
          ushort* __restrict__ oi, float* __restrict__ ws,
          const float* __restrict__ g2, const float* __restrict__ b2) {
    __shared__ __align__(16) ushort zL[2 * 4224];
    __shared__ float finL[128];
    __shared__ float accL[64];
    const int t = threadIdx.x, unit = blockIdx.x;
    const int bi = unit >> 9, f = (unit >> 4) & 31, jb = unit & 15;
    const int g0 = jb * 2, slot = unit & 63;
    const int w = t >> 6, l = t & 63, l15 = l & 15, grp = l >> 4;
    const int pl_ = w >> 1, mh = w & 1;
    const int patch = bi * 1024 + f * 32 + g0 + pl_;

    dev_fin(ws, SLOTS2, SLOTS2Q, g2, b2, 64, 524288.0f, finL, t);
    if (t < 64) accL[t] = 0.f;
    const ushort* wp = st2 + (size_t)patch * 4672;
    FR aw[2];
    #pragma unroll
    for (int ks = 0; ks < 2; ks++)
        aw[ks].u4 = ((const uint4*)(wp + R2c))[(mh * 16 + l15) * 8 + ks * 4 + grp];

    const uint4* zsrc = (const uint4*)(zbuf + (size_t)patch * 4096);
    unsigned int* zd = (unsigned int*)zL;
    #pragma unroll
    for (int it = 0; it < 4; it++) {
        int i = mh * 256 + it * 64 + l;
        uint4 v = zsrc[i];
        int ch = i >> 3, px0 = (i & 7) * 8;
        float a2 = finL[ch], bb2 = finL[64 + ch];
        unsigned int uu[4] = {v.x, v.y, v.z, v.w};
        int base = pl_ * 2112 + (ch * 66 + px0) / 2;
        #pragma unroll
        for (int k = 0; k < 4; k++) {
            float lo = fminf(fmaxf(bf16lo_to_f(uu[k]) * a2 + bb2, 0.f), 6.f);
            float hi = fminf(fmaxf(bf16hi_to_f(uu[k]) * a2 + bb2, 0.f), 6.f);
            zd[base + k] = pack_bf16(lo, hi);
        }
    }
    __syncthreads();

    FR bfr[2][4];
    #pragma unroll
    for (int ks = 0; ks < 2; ks++)
        #pragma unroll
        for (int n = 0; n < 4; n++)
            #pragma unroll
            for (int j = 0; j < 8; j++)
                bfr[ks][n].s[j] = zL[pl_ * 4224 + (ks * 32 + grp * 8 + j) * 66 + n * 16 + l15];

    float s4[4], q4[4];
    #pragma unroll
    for (int r = 0; r < 4; r++) { s4[r] = 0.f; q4[r] = 0.f; }
    #pragma unroll
    for (int n = 0; n < 4; n++) {
        f32x4 z = {0.f, 0.f, 0.f, 0.f};
        f32x4 c = mfma16(aw[0].v, bfr[0][n].v, z);
        c = mfma16(aw[1].v, bfr[1][n].v, c);
        #pragma unroll
        for (int r = 0; r < 4; r++) {
            float v = c[r];
            s4[r] += v; q4[r] += v * v;
            int oc = mh * 16 + grp * 4 + r;
            int px = n * 16 + l15, p = px >> 3, q = px & 7;
            oi[((size_t)(bi * 32 + oc) * 256 + f * 8 + p) * 256 + (g0 + pl_) * 8 + q] = f_to_bf16(v);
        }
    }
    #pragma unroll
    for (int r = 0; r < 4; r++) {
        float sm = s4[r], qq = q4[r];
        #pragma unroll
        for (int msk = 1; msk <= 8; msk <<= 1) { sm += __shfl_xor(sm, msk); qq += __shfl_xor(qq, msk); }
        if (l15 == 0) {
            int oc = mh * 16 + grp * 4 + r;
            atomicAdd(&accL[oc], sm);
            atomicAdd(&accL[32 + oc], qq);
        }
    }
    __syncthreads();
    if (t < 32) {
        atomicAdd(&ws[SLOTS3  + t * 64 + slot], accL[t]);
        atomicAdd(&ws[SLOTS3Q + t * 64 + slot], accL[32 + t]);
    }
}

// ---------------------------------------------------------------------------
// K4: per-block BN3 finalize; out = x + bn3(o), pure float4 stream.
__global__ __launch_bounds__(NT, 8)
void k4_w(const float* __restrict__ x, float* __restrict__ ws,
          const ushort* __restrict__ oi, float* __restrict__ out,
          const float* __restrict__ g3, const float* __restrict__ b3) {
    __shared__ float finL[64];
    dev_fin(ws, SLOTS3, SLOTS3Q, g3, b3, 32, 524288.0f, finL, threadIdx.x);
    #pragma unroll
    for (int it = 0; it < 8; it++) {
        size_t e = ((size_t)(it * 2048 + blockIdx.x) * 256 + threadIdx.x) * 4;
        int oc = (int)((e >> 16) & 31);
        float a3 = finL[oc], bb3 = finL[32 + oc];
        uint2 ov = *(const uint2*)(oi + e);
        float4 xv = *(const float4*)(x + e);
        float4 r;
        r.x = xv.x + bf16lo_to_f(ov.x) * a3 + bb3;
        r.y = xv.y + bf16hi_to_f(ov.x) * a3 + bb3;
        r.z = xv.z + bf16lo_to_f(ov.y) * a3 + bb3;
        r.w = xv.w + bf16hi_to_f(ov.y) * a3 + bb3;
        *(float4*)(out + e) = r;
    }
}

// ---------------------------------------------------------------------------
extern "C" void kernel_launch(void* const* d_in, const int* in_sizes, int n_in,
                              void* d_out, int out_size, void* d_ws, size_t ws_size,
                              hipStream_t stream) {
    const float* x  = (const float*)d_in[0];
    const float* s  = (const float*)d_in[1];
    const float* g1 = (const float*)d_in[2];
    const float* b1 = (const float*)d_in[3];
    const float* g2 = (const float*)d_in[4];
    const float* b2 = (const float*)d_in[5];
    const float* g3 = (const float*)d_in[6];
    const float* b3 = (const float*)d_in[7];
    float* out = (float*)d_out;
    float* ws  = (float*)d_ws;

    ushort* st2 = (ushort*)((char*)d_ws + ST2_OFF);
    ushort* zb  = (ushort*)((char*)d_ws + ZB_OFF);
    ushort* yb  = (ushort*)((char*)d_ws + Y_OFF);
    ushort* oi  = (ushort*)((char*)d_ws + OI_OFF);

    transpose_w<<<18688, 256, 0, stream>>>(s, st2, ws);
    k1_w<<<4096, NT, 0, stream>>>(x, st2, yb, ws);
    k2_w<<<4096, NT, 0, stream>>>(yb, st2, zb, ws, g1, b1);
    k3_w<<<4096, NT, 0, stream>>>(zb, st2, oi, ws, g2, b2);
    k4_w<<<2048, NT, 0, stream>>>(x, ws, oi, out, g3, b3);
}

// Round 14
// 268.950 us; speedup vs baseline: 2.9399x; 1.0716x over previous
//
#include <hip/hip_runtime.h>

#define NT 256

constexpr int R1c = 2048;
constexpr int R2c = 2624;
constexpr float EPSc = 1e-5f;

// ws float offsets (stats)
constexpr int SLOTS1  = 0;
constexpr int SLOTS1Q = 4096;
constexpr int SLOTS2  = 8192;
constexpr int SLOTS2Q = 12288;
constexpr int SLOTS3  = 16384;
constexpr int SLOTS3Q = 18432;
constexpr int STATS_ZERO_FLOATS = 20480;

// ws byte offsets
constexpr size_t ST2_OFF   = 131072;                   // bf16 transposed s
constexpr size_t ST2_BYTES = 8ull * 1024 * 4672 * 2;   // 76,546,048
constexpr size_t ZB_OFF    = ST2_OFF + ST2_BYTES;      // z bf16 [patch][64][64]
constexpr size_t ZB_BYTES  = 8192ull * 4096 * 2;       // 67,108,864
constexpr size_t Y_OFF     = ZB_OFF + ZB_BYTES;        // 143,785,984
constexpr size_t Y_BYTES   = 8192ull * 13312;          // y bf16 [patch][64][104]
constexpr size_t NEED_Y    = Y_OFF + Y_BYTES;          // 252,837,888
constexpr size_t OI_OFF    = Y_OFF;                    // o image overlays dead y

// ---- bf16 helpers -------------------------------------------------------
__device__ __forceinline__ ushort f_to_bf16(float f) {
    union { float f; unsigned int i; } v; v.f = f;
    unsigned int r = (v.i + 0x7fffu + ((v.i >> 16) & 1u)) >> 16;
    return (ushort)r;
}
__device__ __forceinline__ float bf16_to_f(ushort u) {
    union { unsigned int i; float f; } v; v.i = ((unsigned int)u) << 16; return v.f;
}
__device__ __forceinline__ float bf16lo_to_f(unsigned int u) {
    union { unsigned int i; float f; } v; v.i = u << 16; return v.f;
}
__device__ __forceinline__ float bf16hi_to_f(unsigned int u) {
    union { unsigned int i; float f; } v; v.i = u & 0xffff0000u; return v.f;
}
__device__ __forceinline__ unsigned int pack_bf16(float lo, float hi) {
    return (unsigned int)f_to_bf16(lo) | ((unsigned int)f_to_bf16(hi) << 16);
}

typedef short bf16x8 __attribute__((ext_vector_type(8)));
typedef float f32x4  __attribute__((ext_vector_type(4)));
typedef float f32x4n __attribute__((ext_vector_type(4)));   // native vec for nt-store
union FR { uint4 u4; bf16x8 v; ushort s[8]; };

__device__ __forceinline__ f32x4 mfma16(bf16x8 a, bf16x8 b, f32x4 c) {
    return __builtin_amdgcn_mfma_f32_16x16x32_bf16(a, b, c, 0, 0, 0);
}

// per-block finalize from slots: finL[ch]=a, finL[nch+ch]=b.
__device__ __forceinline__ void dev_fin(const float* __restrict__ ws, int so, int sq,
        const float* __restrict__ gamma, const float* __restrict__ beta,
        int nch, float N, float* finL, int t) {
    if (t < nch) {
        float sm = 0.f, qq = 0.f;
        for (int j = 0; j < 64; j++) { sm += ws[so + t*64 + j]; qq += ws[sq + t*64 + j]; }
        float mean = sm / N;
        float var  = qq / N - mean * mean;
        float a = rsqrtf(var + EPSc) * gamma[t];
        finL[t]       = a;
        finL[nch + t] = beta[t] - mean * a;
    }
    __syncthreads();
}

// 64-param x 32-patch transpose tile body (s fp32 -> st2 bf16).
__device__ __forceinline__ void tr_tile(int bi, int p0, int q0, int t,
        const float* __restrict__ s, ushort* __restrict__ st, float* tl) {
    const int tx = t & 31, ty = t >> 5;
    const float* sb = s + (size_t)bi * 4672 * 1024;
    #pragma unroll
    for (int r = ty; r < 64; r += 8)
        tl[r * 33 + tx] = sb[(size_t)(p0 + r) * 1024 + q0 + tx];
    __syncthreads();
    unsigned int* stu = (unsigned int*)(st + (size_t)bi * 1024 * 4672);
    #pragma unroll
    for (int rr = ty; rr < 32; rr += 8) {
        int q = q0 + rr;
        stu[((size_t)q * 4672 + p0) / 2 + tx] =
            pack_bf16(tl[(2 * tx) * 33 + rr], tl[(2 * tx + 1) * 33 + rr]);
    }
}

// ---------------------------------------------------------------------------
// Transpose w1 slice only (tiles px 0..31) + zero stats slots. Grid 8192.
__global__ __launch_bounds__(256)
void transpose_w1(const float* __restrict__ s, ushort* __restrict__ st,
                  float* __restrict__ ws) {
    __shared__ float tl[2112];
    const int blk = blockIdx.x, t = threadIdx.x;
    if (blk < 80) {
        int idx = blk * 256 + t;
        if (idx < STATS_ZERO_FLOATS) ws[idx] = 0.f;
    }
    const int bi = blk >> 10, rem = blk & 1023;
    const int qy = rem >> 5, px = rem & 31;
    tr_tile(bi, px * 64, qy * 32, t, s, st, tl);
}

// ---------------------------------------------------------------------------
// K1: blocks [0,4096): 2 patches, 2 waves/patch, stage-1 MFMA + stats1 + y.
//     blocks [4096,6400): w2 transpose tiles (px 32..40), overlapped.
__global__ __launch_bounds__(NT, 4)
void k1_w(const float* __restrict__ x, const float* __restrict__ s,
          ushort* __restrict__ st2, ushort* __restrict__ ybuf,
          float* __restrict__ ws) {
    __shared__ __align__(16) ushort frB[2 * 3584];
    __shared__ float st1[128];
    const int t = threadIdx.x, unit = blockIdx.x;

    if (unit >= 4096) {   // overlapped w2 transpose
        int u = unit - 4096;
        int bi = u / 288, rem = u - bi * 288;
        int qy = rem / 9, px = 32 + (rem - qy * 9);
        tr_tile(bi, px * 64, qy * 32, t, s, st2, (float*)frB);
        return;
    }

    const int bi = unit >> 9, f = (unit >> 4) & 31, jb = unit & 15;
    const int g0 = jb * 2, slot = unit & 63;
    const int w = t >> 6, l = t & 63, l15 = l & 15, grp = l >> 4;
    const int pl_ = w >> 1, mh = w & 1;
    const int patch = bi * 1024 + f * 32 + g0 + pl_;

    if (t < 128) {
        st1[t] = 0.f;
        int p = t >> 6, e = t & 63;
        if ((e & 15) >= 4)
            ((uint4*)frB)[p * 448 + 384 + e] = make_uint4(0u, 0u, 0u, 0u);
    }
    const ushort* wp = st2 + (size_t)patch * 4672;
    FR aw[2];
    #pragma unroll
    for (int i = 0; i < 2; i++)
        aw[i].u4 = ((const uint4*)wp)[((mh * 2 + i) * 16 + l15) * 4 + grp];

    const float* xb = x + (size_t)bi * 32 * 65536;
    for (int i = t; i < 1920; i += NT) {
        int c = i / 60, rem = i - c * 60;
        int r = rem / 6, seg = rem - r * 6;
        int row = f * 8 - 1 + r; row = row < 0 ? -row : (row > 255 ? 510 - row : row);
        int col0 = g0 * 8 - 4 + seg * 4;
        float v4[4];
        if (col0 >= 0 && col0 <= 252) {
            float4 vv = *(const float4*)(xb + (size_t)c * 65536 + row * 256 + col0);
            v4[0] = vv.x; v4[1] = vv.y; v4[2] = vv.z; v4[3] = vv.w;
        } else {
            #pragma unroll
            for (int d = 0; d < 4; d++) {
                int cc = col0 + d; cc = cc < 0 ? -cc : (cc > 255 ? 510 - cc : cc);
                v4[d] = xb[(size_t)c * 65536 + row * 256 + cc];
            }
        }
        int grpc = c >> 3, j = c & 7;
        #pragma unroll
        for (int d = 0; d < 4; d++) {
            int u = col0 + d - g0 * 8;
            ushort hv = f_to_bf16(v4[d]);
            #pragma unroll
            for (int p = 0; p < 2; p++) {
                int pc = u - 8 * p + 1;
                if (pc >= 0 && pc <= 9) {
                    int px = r * 10 + pc;
                    frB[p * 3584 + ((px >> 4) * 64 + grpc * 16 + (px & 15)) * 8 + j] = hv;
                }
            }
        }
    }
    __syncthreads();

    FR b[7];
    const uint4* bp = (const uint4*)(frB + pl_ * 3584);
    #pragma unroll
    for (int n = 0; n < 7; n++) b[n].u4 = bp[n * 64 + l];
    __syncthreads();   // frag reads done -> overlay safe

    ushort* slice = frB + pl_ * 3584 + mh * 1792;
    unsigned int* sliceU = (unsigned int*)slice;
    uint4* yb4 = (uint4*)ybuf + (size_t)patch * 832;
    float s4[8], q4[8];
    #pragma unroll
    for (int i = 0; i < 8; i++) { s4[i] = 0.f; q4[i] = 0.f; }
    #pragma unroll
    for (int i = 0; i < 2; i++) {
        int mm = mh * 2 + i;
        #pragma unroll
        for (int n = 0; n < 7; n++) {
            f32x4 z = {0.f, 0.f, 0.f, 0.f};
            f32x4 c = mfma16(aw[i].v, b[n].v, z);
            int px = n * 16 + l15;
            #pragma unroll
            for (int r = 0; r < 4; r++) {
                float v = c[r]; s4[i*4+r] += v; q4[i*4+r] += v * v;
                if (px < 100) slice[(grp * 4 + r) * 106 + px] = f_to_bf16(v);
            }
        }
        for (int k = l; k < 208; k += 64) {
            int ch2 = k / 13, sub = k - ch2 * 13;
            int ub = ch2 * 53 + sub * 4;
            yb4[mm * 208 + k] = make_uint4(sliceU[ub], sliceU[ub+1], sliceU[ub+2], sliceU[ub+3]);
        }
    }
    #pragma unroll
    for (int i = 0; i < 8; i++) {
        float sm = s4[i], qq = q4[i];
        #pragma unroll
        for (int msk = 1; msk <= 8; msk <<= 1) { sm += __shfl_xor(sm, msk); qq += __shfl_xor(qq, msk); }
        if (l15 == 0) {
            int ch = (mh * 2 + (i >> 2)) * 16 + grp * 4 + (i & 3);
            atomicAdd(&st1[ch], sm);
            atomicAdd(&st1[64 + ch], qq);
        }
    }
    __syncthreads();
    if (t < 64) {
        atomicAdd(&ws[SLOTS1  + t * 64 + slot], st1[t]);
        atomicAdd(&ws[SLOTS1Q + t * 64 + slot], st1[64 + t]);
    }
}

// ---------------------------------------------------------------------------
// K2: blocks [0,4096): BN1 finalize + y->depthwise->stats2->z.
//     blocks [4096,12288): w3 transpose tiles (px 41..72), overlapped.
__global__ __launch_bounds__(NT, 4)
void k2_w(const ushort* __restrict__ ybuf, const float* __restrict__ s,
          ushort* __restrict__ st2, ushort* __restrict__ zbuf,
          float* __restrict__ ws,
          const float* __restrict__ g1, const float* __restrict__ b1) {
    __shared__ __align__(16) ushort slc[4 * 1696];
    __shared__ unsigned int w2L[2 * 288];
    __shared__ float finL[128];
    __shared__ float accL[128];
    const int t = threadIdx.x, unit = blockIdx.x;

    if (unit >= 4096) {   // overlapped w3 transpose
        int u = unit - 4096;
        int bi = u >> 10, rem = u & 1023;
        int qy = rem >> 5, px = 41 + (rem & 31);
        tr_tile(bi, px * 64, qy * 32, t, s, st2, (float*)slc);
        return;
    }

    const int bi = unit >> 9, f = (unit >> 4) & 31, jb = unit & 15;
    const int g0 = jb * 2, slot = unit & 63;
    const int w = t >> 6, l = t & 63;
    const int pl_ = w >> 1, mh = w & 1;
    const int ch_l = l >> 2, quad = l & 3, p0 = quad * 2;
    const int patch = bi * 1024 + f * 32 + g0 + pl_;

    dev_fin(ws, SLOTS1, SLOTS1Q, g1, b1, 64, 819200.0f, finL, t);
    if (t < 128) accL[t] = 0.f;
    for (int k = t; k < 576; k += NT) {
        int p = (k >= 288) ? 1 : 0;
        int kk = k - p * 288;
        const unsigned int* src = (const unsigned int*)(st2 + (size_t)(bi*1024 + f*32 + g0 + p) * 4672 + R1c);
        w2L[k] = src[kk];
    }
    __syncthreads();

    const uint4* yb4 = (const uint4*)ybuf + (size_t)patch * 832;
    ushort* slice = slc + w * 1696;
    unsigned int* sliceU = (unsigned int*)slice;
    const ushort* w2u = (const ushort*)(w2L + pl_ * 288);
    ushort* zp0 = zbuf + (size_t)patch * 4096;

    #pragma unroll
    for (int i = 0; i < 2; i++) {
        int mm = mh * 2 + i;
        for (int k = l; k < 208; k += 64) {
            uint4 v = yb4[mm * 208 + k];
            int ch2 = k / 13, sub = k - ch2 * 13;
            int ch = mm * 16 + ch2;
            float a1 = finL[ch], bb1 = finL[64 + ch];
            unsigned int uu[4] = {v.x, v.y, v.z, v.w};
            int ub = ch2 * 53 + sub * 4;
            #pragma unroll
            for (int kk = 0; kk < 4; kk++) {
                float lo = fminf(fmaxf(bf16lo_to_f(uu[kk]) * a1 + bb1, 0.f), 6.f);
                float hi = fminf(fmaxf(bf16hi_to_f(uu[kk]) * a1 + bb1, 0.f), 6.f);
                sliceU[ub + kk] = pack_bf16(lo, hi);
            }
        }
        float yv[4][10];
        #pragma unroll
        for (int rr = 0; rr < 4; rr++) {
            int base = ch_l * 53 + (p0 + rr) * 5;
            #pragma unroll
            for (int k = 0; k < 5; k++) {
                unsigned int u = sliceU[base + k];
                yv[rr][2*k] = bf16lo_to_f(u); yv[rr][2*k+1] = bf16hi_to_f(u);
            }
        }
        float wt[9];
        #pragma unroll
        for (int k = 0; k < 9; k++) wt[k] = bf16_to_f(w2u[(mm * 16 + ch_l) * 9 + k]);
        float za[2][8];
        #pragma unroll
        for (int rr = 0; rr < 2; rr++)
            #pragma unroll
            for (int q = 0; q < 8; q++) za[rr][q] = 0.f;
        #pragma unroll
        for (int u = 0; u < 3; u++)
            #pragma unroll
            for (int v = 0; v < 3; v++) {
                float wv = wt[u * 3 + v];
                #pragma unroll
                for (int rr = 0; rr < 2; rr++)
                    #pragma unroll
                    for (int q = 0; q < 8; q++)
                        za[rr][q] += wv * yv[rr + u][q + v];
            }
        float zs = 0.f, zq = 0.f;
        #pragma unroll
        for (int rr = 0; rr < 2; rr++)
            #pragma unroll
            for (int q = 0; q < 8; q++) { float v = za[rr][q]; zs += v; zq += v * v; }
        zs += __shfl_xor(zs, 1); zs += __shfl_xor(zs, 2);
        zq += __shfl_xor(zq, 1); zq += __shfl_xor(zq, 2);
        if (quad == 0) {
            atomicAdd(&accL[mm * 16 + ch_l], zs);
            atomicAdd(&accL[64 + mm * 16 + ch_l], zq);
        }
        ushort* zp = zp0 + (mm * 16 + ch_l) * 64 + p0 * 8;
        uint4 pk0, pk1;
        pk0.x = pack_bf16(za[0][0], za[0][1]); pk0.y = pack_bf16(za[0][2], za[0][3]);
        pk0.z = pack_bf16(za[0][4], za[0][5]); pk0.w = pack_bf16(za[0][6], za[0][7]);
        pk1.x = pack_bf16(za[1][0], za[1][1]); pk1.y = pack_bf16(za[1][2], za[1][3]);
        pk1.z = pack_bf16(za[1][4], za[1][5]); pk1.w = pack_bf16(za[1][6], za[1][7]);
        *(uint4*)zp = pk0;
        *(uint4*)(zp + 8) = pk1;
    }
    __syncthreads();
    if (t < 64) {
        atomicAdd(&ws[SLOTS2  + t * 64 + slot], accL[t]);
        atomicAdd(&ws[SLOTS2Q + t * 64 + slot], accL[64 + t]);
    }
}

// ---------------------------------------------------------------------------
// K3: per-block BN2 finalize; z -> BN2+relu6 -> MFMA -> stats3 + o image.
__global__ __launch_bounds__(NT, 4)
void k3_w(const ushort* __restrict__ zbuf, const ushort* __restrict__ st2,
          ushort* __restrict__ oi, float* __restrict__ ws,
          const float* __restrict__ g2, const float* __restrict__ b2) {
    __shared__ __align__(16) ushort zL[2 * 4224];
    __shared__ float finL[128];
    __shared__ float accL[64];
    const int t = threadIdx.x, unit = blockIdx.x;
    const int bi = unit >> 9, f = (unit >> 4) & 31, jb = unit & 15;
    const int g0 = jb * 2, slot = unit & 63;
    const int w = t >> 6, l = t & 63, l15 = l & 15, grp = l >> 4;
    const int pl_ = w >> 1, mh = w & 1;
    const int patch = bi * 1024 + f * 32 + g0 + pl_;

    dev_fin(ws, SLOTS2, SLOTS2Q, g2, b2, 64, 524288.0f, finL, t);
    if (t < 64) accL[t] = 0.f;
    const ushort* wp = st2 + (size_t)patch * 4672;
    FR aw[2];
    #pragma unroll
    for (int ks = 0; ks < 2; ks++)
        aw[ks].u4 = ((const uint4*)(wp + R2c))[(mh * 16 + l15) * 8 + ks * 4 + grp];

    const uint4* zsrc = (const uint4*)(zbuf + (size_t)patch * 4096);
    unsigned int* zd = (unsigned int*)zL;
    #pragma unroll
    for (int it = 0; it < 4; it++) {
        int i = mh * 256 + it * 64 + l;
        uint4 v = zsrc[i];
        int ch = i >> 3, px0 = (i & 7) * 8;
        float a2 = finL[ch], bb2 = finL[64 + ch];
        unsigned int uu[4] = {v.x, v.y, v.z, v.w};
        int base = pl_ * 2112 + (ch * 66 + px0) / 2;
        #pragma unroll
        for (int k = 0; k < 4; k++) {
            float lo = fminf(fmaxf(bf16lo_to_f(uu[k]) * a2 + bb2, 0.f), 6.f);
            float hi = fminf(fmaxf(bf16hi_to_f(uu[k]) * a2 + bb2, 0.f), 6.f);
            zd[base + k] = pack_bf16(lo, hi);
        }
    }
    __syncthreads();

    FR bfr[2][4];
    #pragma unroll
    for (int ks = 0; ks < 2; ks++)
        #pragma unroll
        for (int n = 0; n < 4; n++)
            #pragma unroll
            for (int j = 0; j < 8; j++)
                bfr[ks][n].s[j] = zL[pl_ * 4224 + (ks * 32 + grp * 8 + j) * 66 + n * 16 + l15];

    float s4[4], q4[4];
    #pragma unroll
    for (int r = 0; r < 4; r++) { s4[r] = 0.f; q4[r] = 0.f; }
    #pragma unroll
    for (int n = 0; n < 4; n++) {
        f32x4 z = {0.f, 0.f, 0.f, 0.f};
        f32x4 c = mfma16(aw[0].v, bfr[0][n].v, z);
        c = mfma16(aw[1].v, bfr[1][n].v, c);
        #pragma unroll
        for (int r = 0; r < 4; r++) {
            float v = c[r];
            s4[r] += v; q4[r] += v * v;
            int oc = mh * 16 + grp * 4 + r;
            int px = n * 16 + l15, p = px >> 3, q = px & 7;
            oi[((size_t)(bi * 32 + oc) * 256 + f * 8 + p) * 256 + (g0 + pl_) * 8 + q] = f_to_bf16(v);
        }
    }
    #pragma unroll
    for (int r = 0; r < 4; r++) {
        float sm = s4[r], qq = q4[r];
        #pragma unroll
        for (int msk = 1; msk <= 8; msk <<= 1) { sm += __shfl_xor(sm, msk); qq += __shfl_xor(qq, msk); }
        if (l15 == 0) {
            int oc = mh * 16 + grp * 4 + r;
            atomicAdd(&accL[oc], sm);
            atomicAdd(&accL[32 + oc], qq);
        }
    }
    __syncthreads();
    if (t < 32) {
        atomicAdd(&ws[SLOTS3  + t * 64 + slot], accL[t]);
        atomicAdd(&ws[SLOTS3Q + t * 64 + slot], accL[32 + t]);
    }
}

// ---------------------------------------------------------------------------
// K4: per-block BN3 finalize; out = x + bn3(o), nontemporal float4 stream.
__global__ __launch_bounds__(NT, 8)
void k4_w(const float* __restrict__ x, float* __restrict__ ws,
          const ushort* __restrict__ oi, float* __restrict__ out,
          const float* __restrict__ g3, const float* __restrict__ b3) {
    __shared__ float finL[64];
    dev_fin(ws, SLOTS3, SLOTS3Q, g3, b3, 32, 524288.0f, finL, threadIdx.x);
    #pragma unroll
    for (int it = 0; it < 8; it++) {
        size_t e = ((size_t)(it * 2048 + blockIdx.x) * 256 + threadIdx.x) * 4;
        int oc = (int)((e >> 16) & 31);
        float a3 = finL[oc], bb3 = finL[32 + oc];
        uint2 ov = *(const uint2*)(oi + e);
        float4 xv = *(const float4*)(x + e);
        f32x4n r;
        r.x = xv.x + bf16lo_to_f(ov.x) * a3 + bb3;
        r.y = xv.y + bf16hi_to_f(ov.x) * a3 + bb3;
        r.z = xv.z + bf16lo_to_f(ov.y) * a3 + bb3;
        r.w = xv.w + bf16hi_to_f(ov.y) * a3 + bb3;
        __builtin_nontemporal_store(r, (f32x4n*)(out + e));
    }
}

// ---------------------------------------------------------------------------
extern "C" void kernel_launch(void* const* d_in, const int* in_sizes, int n_in,
                              void* d_out, int out_size, void* d_ws, size_t ws_size,
                              hipStream_t stream) {
    const float* x  = (const float*)d_in[0];
    const float* s  = (const float*)d_in[1];
    const float* g1 = (const float*)d_in[2];
    const float* b1 = (const float*)d_in[3];
    const float* g2 = (const float*)d_in[4];
    const float* b2 = (const float*)d_in[5];
    const float* g3 = (const float*)d_in[6];
    const float* b3 = (const float*)d_in[7];
    float* out = (float*)d_out;
    float* ws  = (float*)d_ws;

    ushort* st2 = (ushort*)((char*)d_ws + ST2_OFF);
    ushort* zb  = (ushort*)((char*)d_ws + ZB_OFF);
    ushort* yb  = (ushort*)((char*)d_ws + Y_OFF);
    ushort* oi  = (ushort*)((char*)d_ws + OI_OFF);

    transpose_w1<<<8192, 256, 0, stream>>>(s, st2, ws);
    k1_w<<<6400, NT, 0, stream>>>(x, s, st2, yb, ws);
    k2_w<<<12288, NT, 0, stream>>>(yb, s, st2, zb, ws, g1, b1);
    k3_w<<<4096, NT, 0, stream>>>(zb, st2, oi, ws, g2, b2);
    k4_w<<<2048, NT, 0, stream>>>(x, ws, oi, out, g3, b3);
}

// Round 15
// 263.234 us; speedup vs baseline: 3.0037x; 1.0217x over previous
//
#include <hip/hip_runtime.h>

#define NT 256

constexpr int R1c = 2048;
constexpr int R2c = 2624;
constexpr float EPSc = 1e-5f;

// ws float offsets (stats)
constexpr int SLOTS1  = 0;
constexpr int SLOTS1Q = 4096;
constexpr int SLOTS2  = 8192;
constexpr int SLOTS2Q = 12288;
constexpr int SLOTS3  = 16384;
constexpr int SLOTS3Q = 18432;
constexpr int STATS_ZERO_FLOATS = 20480;

// ws byte offsets
constexpr size_t ST2_OFF   = 131072;                   // bf16 transposed s
constexpr size_t ST2_BYTES = 8ull * 1024 * 4672 * 2;   // 76,546,048
constexpr size_t ZB_OFF    = ST2_OFF + ST2_BYTES;      // z bf16 [patch][64][64]
constexpr size_t ZB_BYTES  = 8192ull * 4096 * 2;       // 67,108,864
constexpr size_t Y_OFF     = ZB_OFF + ZB_BYTES;        // 143,785,984
constexpr size_t Y_BYTES   = 8192ull * 12800;          // y bf16 frag layout [patch][4][800 uints]
constexpr size_t OI_OFF    = Y_OFF;                    // o image overlays dead y

// ---- bf16 helpers -------------------------------------------------------
__device__ __forceinline__ ushort f_to_bf16(float f) {
    union { float f; unsigned int i; } v; v.f = f;
    unsigned int r = (v.i + 0x7fffu + ((v.i >> 16) & 1u)) >> 16;
    return (ushort)r;
}
__device__ __forceinline__ float bf16_to_f(ushort u) {
    union { unsigned int i; float f; } v; v.i = ((unsigned int)u) << 16; return v.f;
}
__device__ __forceinline__ float bf16lo_to_f(unsigned int u) {
    union { unsigned int i; float f; } v; v.i = u << 16; return v.f;
}
__device__ __forceinline__ float bf16hi_to_f(unsigned int u) {
    union { unsigned int i; float f; } v; v.i = u & 0xffff0000u; return v.f;
}
__device__ __forceinline__ unsigned int pack_bf16(float lo, float hi) {
    return (unsigned int)f_to_bf16(lo) | ((unsigned int)f_to_bf16(hi) << 16);
}

typedef short bf16x8 __attribute__((ext_vector_type(8)));
typedef float f32x4  __attribute__((ext_vector_type(4)));
typedef float f32x4n __attribute__((ext_vector_type(4)));   // native vec for nt-store
union FR { uint4 u4; bf16x8 v; ushort s[8]; };

__device__ __forceinline__ f32x4 mfma16(bf16x8 a, bf16x8 b, f32x4 c) {
    return __builtin_amdgcn_mfma_f32_16x16x32_bf16(a, b, c, 0, 0, 0);
}

// per-block finalize from slots: finL[ch]=a, finL[nch+ch]=b.
__device__ __forceinline__ void dev_fin(const float* __restrict__ ws, int so, int sq,
        const float* __restrict__ gamma, const float* __restrict__ beta,
        int nch, float N, float* finL, int t) {
    if (t < nch) {
        float sm = 0.f, qq = 0.f;
        for (int j = 0; j < 64; j++) { sm += ws[so + t*64 + j]; qq += ws[sq + t*64 + j]; }
        float mean = sm / N;
        float var  = qq / N - mean * mean;
        float a = rsqrtf(var + EPSc) * gamma[t];
        finL[t]       = a;
        finL[nch + t] = beta[t] - mean * a;
    }
    __syncthreads();
}

// 64-param x 32-patch transpose tile body (s fp32 -> st2 bf16).
__device__ __forceinline__ void tr_tile(int bi, int p0, int q0, int t,
        const float* __restrict__ s, ushort* __restrict__ st, float* tl) {
    const int tx = t & 31, ty = t >> 5;
    const float* sb = s + (size_t)bi * 4672 * 1024;
    #pragma unroll
    for (int r = ty; r < 64; r += 8)
        tl[r * 33 + tx] = sb[(size_t)(p0 + r) * 1024 + q0 + tx];
    __syncthreads();
    unsigned int* stu = (unsigned int*)(st + (size_t)bi * 1024 * 4672);
    #pragma unroll
    for (int rr = ty; rr < 32; rr += 8) {
        int q = q0 + rr;
        stu[((size_t)q * 4672 + p0) / 2 + tx] =
            pack_bf16(tl[(2 * tx) * 33 + rr], tl[(2 * tx + 1) * 33 + rr]);
    }
}

// ---------------------------------------------------------------------------
// Transpose w1 slice only (tiles px 0..31) + zero stats slots. Grid 8192.
__global__ __launch_bounds__(256)
void transpose_w1(const float* __restrict__ s, ushort* __restrict__ st,
                  float* __restrict__ ws) {
    __shared__ float tl[2112];
    const int blk = blockIdx.x, t = threadIdx.x;
    if (blk < 80) {
        int idx = blk * 256 + t;
        if (idx < STATS_ZERO_FLOATS) ws[idx] = 0.f;
    }
    const int bi = blk >> 10, rem = blk & 1023;
    const int qy = rem >> 5, px = rem & 31;
    tr_tile(bi, px * 64, qy * 32, t, s, st, tl);
}

// ---------------------------------------------------------------------------
// K1: blocks [0,4096): 2 patches, 2 waves/patch, stage-1 MFMA + stats1 +
//     y stored DIRECTLY in fragment layout [patch][mm(4)][n-packed 800 uints].
//     blocks [4096,6400): w2 transpose tiles (px 32..40), overlapped.
__global__ __launch_bounds__(NT, 4)
void k1_w(const float* __restrict__ x, const float* __restrict__ s,
          ushort* __restrict__ st2, ushort* __restrict__ ybuf,
          float* __restrict__ ws) {
    __shared__ __align__(16) ushort frB[2 * 3584];
    __shared__ float st1[128];
    const int t = threadIdx.x, unit = blockIdx.x;

    if (unit >= 4096) {   // overlapped w2 transpose
        int u = unit - 4096;
        int bi = u / 288, rem = u - bi * 288;
        int qy = rem / 9, px = 32 + (rem - qy * 9);
        tr_tile(bi, px * 64, qy * 32, t, s, st2, (float*)frB);
        return;
    }

    const int bi = unit >> 9, f = (unit >> 4) & 31, jb = unit & 15;
    const int g0 = jb * 2, slot = unit & 63;
    const int w = t >> 6, l = t & 63, l15 = l & 15, grp = l >> 4;
    const int pl_ = w >> 1, mh = w & 1;
    const int patch = bi * 1024 + f * 32 + g0 + pl_;

    if (t < 128) {
        st1[t] = 0.f;
        int p = t >> 6, e = t & 63;
        if ((e & 15) >= 4)
            ((uint4*)frB)[p * 448 + 384 + e] = make_uint4(0u, 0u, 0u, 0u);
    }
    const ushort* wp = st2 + (size_t)patch * 4672;
    FR aw[2];
    #pragma unroll
    for (int i = 0; i < 2; i++)
        aw[i].u4 = ((const uint4*)wp)[((mh * 2 + i) * 16 + l15) * 4 + grp];

    const float* xb = x + (size_t)bi * 32 * 65536;
    for (int i = t; i < 1920; i += NT) {
        int c = i / 60, rem = i - c * 60;
        int r = rem / 6, seg = rem - r * 6;
        int row = f * 8 - 1 + r; row = row < 0 ? -row : (row > 255 ? 510 - row : row);
        int col0 = g0 * 8 - 4 + seg * 4;
        float v4[4];
        if (col0 >= 0 && col0 <= 252) {
            float4 vv = *(const float4*)(xb + (size_t)c * 65536 + row * 256 + col0);
            v4[0] = vv.x; v4[1] = vv.y; v4[2] = vv.z; v4[3] = vv.w;
        } else {
            #pragma unroll
            for (int d = 0; d < 4; d++) {
                int cc = col0 + d; cc = cc < 0 ? -cc : (cc > 255 ? 510 - cc : cc);
                v4[d] = xb[(size_t)c * 65536 + row * 256 + cc];
            }
        }
        int grpc = c >> 3, j = c & 7;
        #pragma unroll
        for (int d = 0; d < 4; d++) {
            int u = col0 + d - g0 * 8;
            ushort hv = f_to_bf16(v4[d]);
            #pragma unroll
            for (int p = 0; p < 2; p++) {
                int pc = u - 8 * p + 1;
                if (pc >= 0 && pc <= 9) {
                    int px = r * 10 + pc;
                    frB[p * 3584 + ((px >> 4) * 64 + grpc * 16 + (px & 15)) * 8 + j] = hv;
                }
            }
        }
    }
    __syncthreads();

    FR b[7];
    const uint4* bp = (const uint4*)(frB + pl_ * 3584);
    #pragma unroll
    for (int n = 0; n < 7; n++) b[n].u4 = bp[n * 64 + l];

    unsigned int* ybp = (unsigned int*)ybuf + (size_t)patch * 3200;
    float s4[8], q4[8];
    #pragma unroll
    for (int i = 0; i < 8; i++) { s4[i] = 0.f; q4[i] = 0.f; }
    #pragma unroll
    for (int i = 0; i < 2; i++) {
        int mm = mh * 2 + i;
        #pragma unroll
        for (int n = 0; n < 7; n++) {
            f32x4 z = {0.f, 0.f, 0.f, 0.f};
            f32x4 c = mfma16(aw[i].v, b[n].v, z);
            #pragma unroll
            for (int r = 0; r < 4; r++) {
                float v = c[r]; s4[i*4+r] += v; q4[i*4+r] += v * v;
            }
            uint2 pk;
            pk.x = pack_bf16(c[0], c[1]);
            pk.y = pack_bf16(c[2], c[3]);
            if (n < 6) {
                *(uint2*)(ybp + mm * 800 + n * 128 + l * 2) = pk;
            } else if (l15 < 4) {
                *(uint2*)(ybp + mm * 800 + 768 + (grp * 4 + l15) * 2) = pk;
            }
        }
    }
    #pragma unroll
    for (int i = 0; i < 8; i++) {
        float sm = s4[i], qq = q4[i];
        #pragma unroll
        for (int msk = 1; msk <= 8; msk <<= 1) { sm += __shfl_xor(sm, msk); qq += __shfl_xor(qq, msk); }
        if (l15 == 0) {
            int ch = (mh * 2 + (i >> 2)) * 16 + grp * 4 + (i & 3);
            atomicAdd(&st1[ch], sm);
            atomicAdd(&st1[64 + ch], qq);
        }
    }
    __syncthreads();
    if (t < 64) {
        atomicAdd(&ws[SLOTS1  + t * 64 + slot], st1[t]);
        atomicAdd(&ws[SLOTS1Q + t * 64 + slot], st1[64 + t]);
    }
}

// ---------------------------------------------------------------------------
// K2: blocks [0,4096): BN1 finalize + y(frag layout)->BN1+relu6->slice->
//     depthwise->stats2->z.  blocks [4096,12288): w3 transpose, overlapped.
__global__ __launch_bounds__(NT, 4)
void k2_w(const ushort* __restrict__ ybuf, const float* __restrict__ s,
          ushort* __restrict__ st2, ushort* __restrict__ zbuf,
          float* __restrict__ ws,
          const float* __restrict__ g1, const float* __restrict__ b1) {
    __shared__ __align__(16) ushort slc[4 * 1696];
    __shared__ unsigned int w2L[2 * 288];
    __shared__ float finL[128];
    __shared__ float accL[128];
    const int t = threadIdx.x, unit = blockIdx.x;

    if (unit >= 4096) {   // overlapped w3 transpose
        int u = unit - 4096;
        int bi = u >> 10, rem = u & 1023;
        int qy = rem >> 5, px = 41 + (rem & 31);
        tr_tile(bi, px * 64, qy * 32, t, s, st2, (float*)slc);
        return;
    }

    const int bi = unit >> 9, f = (unit >> 4) & 31, jb = unit & 15;
    const int g0 = jb * 2, slot = unit & 63;
    const int w = t >> 6, l = t & 63, l15 = l & 15, grp = l >> 4;
    const int pl_ = w >> 1, mh = w & 1;
    const int ch_l = l >> 2, quad = l & 3, p0 = quad * 2;
    const int patch = bi * 1024 + f * 32 + g0 + pl_;

    dev_fin(ws, SLOTS1, SLOTS1Q, g1, b1, 64, 819200.0f, finL, t);
    if (t < 128) accL[t] = 0.f;
    for (int k = t; k < 576; k += NT) {
        int p = (k >= 288) ? 1 : 0;
        int kk = k - p * 288;
        const unsigned int* src = (const unsigned int*)(st2 + (size_t)(bi*1024 + f*32 + g0 + p) * 4672 + R1c);
        w2L[k] = src[kk];
    }
    __syncthreads();

    const unsigned int* ybp = (const unsigned int*)ybuf + (size_t)patch * 3200;
    ushort* slice = slc + w * 1696;     // [16 ch][106] ushorts
    unsigned int* sliceU = (unsigned int*)slice;
    const ushort* w2u = (const ushort*)(w2L + pl_ * 288);
    ushort* zp0 = zbuf + (size_t)patch * 4096;

    #pragma unroll
    for (int i = 0; i < 2; i++) {
        int mm = mh * 2 + i;
        // unpack y frags -> BN1+relu6 -> slice ushorts
        int chb = grp * 4;          // local channel base within 16-ch tile
        float a0 = finL[mm*16 + chb],     bb0 = finL[64 + mm*16 + chb];
        float a1 = finL[mm*16 + chb + 1], bb1 = finL[64 + mm*16 + chb + 1];
        float a2 = finL[mm*16 + chb + 2], bb2 = finL[64 + mm*16 + chb + 2];
        float a3 = finL[mm*16 + chb + 3], bb3 = finL[64 + mm*16 + chb + 3];
        #pragma unroll
        for (int n = 0; n < 7; n++) {
            if (n < 6 || l15 < 4) {
                uint2 v = (n < 6)
                    ? *(const uint2*)(ybp + mm * 800 + n * 128 + l * 2)
                    : *(const uint2*)(ybp + mm * 800 + 768 + (grp * 4 + l15) * 2);
                int px = (n < 6) ? (n * 16 + l15) : (96 + l15);
                float e0 = fminf(fmaxf(bf16lo_to_f(v.x) * a0 + bb0, 0.f), 6.f);
                float e1 = fminf(fmaxf(bf16hi_to_f(v.x) * a1 + bb1, 0.f), 6.f);
                float e2 = fminf(fmaxf(bf16lo_to_f(v.y) * a2 + bb2, 0.f), 6.f);
                float e3 = fminf(fmaxf(bf16hi_to_f(v.y) * a3 + bb3, 0.f), 6.f);
                slice[(chb + 0) * 106 + px] = f_to_bf16(e0);
                slice[(chb + 1) * 106 + px] = f_to_bf16(e1);
                slice[(chb + 2) * 106 + px] = f_to_bf16(e2);
                slice[(chb + 3) * 106 + px] = f_to_bf16(e3);
            }
        }
        // depthwise 3x3 (wave-local slice)
        float yv[4][10];
        #pragma unroll
        for (int rr = 0; rr < 4; rr++) {
            int base = ch_l * 53 + (p0 + rr) * 5;
            #pragma unroll
            for (int k = 0; k < 5; k++) {
                unsigned int u = sliceU[base + k];
                yv[rr][2*k] = bf16lo_to_f(u); yv[rr][2*k+1] = bf16hi_to_f(u);
            }
        }
        float wt[9];
        #pragma unroll
        for (int k = 0; k < 9; k++) wt[k] = bf16_to_f(w2u[(mm * 16 + ch_l) * 9 + k]);
        float za[2][8];
        #pragma unroll
        for (int rr = 0; rr < 2; rr++)
            #pragma unroll
            for (int q = 0; q < 8; q++) za[rr][q] = 0.f;
        #pragma unroll
        for (int u = 0; u < 3; u++)
            #pragma unroll
            for (int v = 0; v < 3; v++) {
                float wv = wt[u * 3 + v];
                #pragma unroll
                for (int rr = 0; rr < 2; rr++)
                    #pragma unroll
                    for (int q = 0; q < 8; q++)
                        za[rr][q] += wv * yv[rr + u][q + v];
            }
        float zs = 0.f, zq = 0.f;
        #pragma unroll
        for (int rr = 0; rr < 2; rr++)
            #pragma unroll
            for (int q = 0; q < 8; q++) { float v = za[rr][q]; zs += v; zq += v * v; }
        zs += __shfl_xor(zs, 1); zs += __shfl_xor(zs, 2);
        zq += __shfl_xor(zq, 1); zq += __shfl_xor(zq, 2);
        if (quad == 0) {
            atomicAdd(&accL[mm * 16 + ch_l], zs);
            atomicAdd(&accL[64 + mm * 16 + ch_l], zq);
        }
        ushort* zp = zp0 + (mm * 16 + ch_l) * 64 + p0 * 8;
        uint4 pk0, pk1;
        pk0.x = pack_bf16(za[0][0], za[0][1]); pk0.y = pack_bf16(za[0][2], za[0][3]);
        pk0.z = pack_bf16(za[0][4], za[0][5]); pk0.w = pack_bf16(za[0][6], za[0][7]);
        pk1.x = pack_bf16(za[1][0], za[1][1]); pk1.y = pack_bf16(za[1][2], za[1][3]);
        pk1.z = pack_bf16(za[1][4], za[1][5]); pk1.w = pack_bf16(za[1][6], za[1][7]);
        *(uint4*)zp = pk0;
        *(uint4*)(zp + 8) = pk1;
    }
    __syncthreads();
    if (t < 64) {
        atomicAdd(&ws[SLOTS2  + t * 64 + slot], accL[t]);
        atomicAdd(&ws[SLOTS2Q + t * 64 + slot], accL[64 + t]);
    }
}

// ---------------------------------------------------------------------------
// K3: per-block BN2 finalize; z -> BN2+relu6 -> MFMA -> stats3 + o image.
__global__ __launch_bounds__(NT, 4)
void k3_w(const ushort* __restrict__ zbuf, const ushort* __restrict__ st2,
          ushort* __restrict__ oi, float* __restrict__ ws,
          const float* __restrict__ g2, const float* __restrict__ b2) {
    __shared__ __align__(16) ushort zL[2 * 4224];
    __shared__ float finL[128];
    __shared__ float accL[64];
    const int t = threadIdx.x, unit = blockIdx.x;
    const int bi = unit >> 9, f = (unit >> 4) & 31, jb = unit & 15;
    const int g0 = jb * 2, slot = unit & 63;
    const int w = t >> 6, l = t & 63, l15 = l & 15, grp = l >> 4;
    const int pl_ = w >> 1, mh = w & 1;
    const int patch = bi * 1024 + f * 32 + g0 + pl_;

    dev_fin(ws, SLOTS2, SLOTS2Q, g2, b2, 64, 524288.0f, finL, t);
    if (t < 64) accL[t] = 0.f;
    const ushort* wp = st2 + (size_t)patch * 4672;
    FR aw[2];
    #pragma unroll
    for (int ks = 0; ks < 2; ks++)
        aw[ks].u4 = ((const uint4*)(wp + R2c))[(mh * 16 + l15) * 8 + ks * 4 + grp];

    const uint4* zsrc = (const uint4*)(zbuf + (size_t)patch * 4096);
    unsigned int* zd = (unsigned int*)zL;
    #pragma unroll
    for (int it = 0; it < 4; it++) {
        int i = mh * 256 + it * 64 + l;
        uint4 v = zsrc[i];
        int ch = i >> 3, px0 = (i & 7) * 8;
        float a2 = finL[ch], bb2 = finL[64 + ch];
        unsigned int uu[4] = {v.x, v.y, v.z, v.w};
        int base = pl_ * 2112 + (ch * 66 + px0) / 2;
        #pragma unroll
        for (int k = 0; k < 4; k++) {
            float lo = fminf(fmaxf(bf16lo_to_f(uu[k]) * a2 + bb2, 0.f), 6.f);
            float hi = fminf(fmaxf(bf16hi_to_f(uu[k]) * a2 + bb2, 0.f), 6.f);
            zd[base + k] = pack_bf16(lo, hi);
        }
    }
    __syncthreads();

    FR bfr[2][4];
    #pragma unroll
    for (int ks = 0; ks < 2; ks++)
        #pragma unroll
        for (int n = 0; n < 4; n++)
            #pragma unroll
            for (int j = 0; j < 8; j++)
                bfr[ks][n].s[j] = zL[pl_ * 4224 + (ks * 32 + grp * 8 + j) * 66 + n * 16 + l15];

    float s4[4], q4[4];
    #pragma unroll
    for (int r = 0; r < 4; r++) { s4[r] = 0.f; q4[r] = 0.f; }
    #pragma unroll
    for (int n = 0; n < 4; n++) {
        f32x4 z = {0.f, 0.f, 0.f, 0.f};
        f32x4 c = mfma16(aw[0].v, bfr[0][n].v, z);
        c = mfma16(aw[1].v, bfr[1][n].v, c);
        #pragma unroll
        for (int r = 0; r < 4; r++) {
            float v = c[r];
            s4[r] += v; q4[r] += v * v;
            int oc = mh * 16 + grp * 4 + r;
            int px = n * 16 + l15, p = px >> 3, q = px & 7;
            oi[((size_t)(bi * 32 + oc) * 256 + f * 8 + p) * 256 + (g0 + pl_) * 8 + q] = f_to_bf16(v);
        }
    }
    #pragma unroll
    for (int r = 0; r < 4; r++) {
        float sm = s4[r], qq = q4[r];
        #pragma unroll
        for (int msk = 1; msk <= 8; msk <<= 1) { sm += __shfl_xor(sm, msk); qq += __shfl_xor(qq, msk); }
        if (l15 == 0) {
            int oc = mh * 16 + grp * 4 + r;
            atomicAdd(&accL[oc], sm);
            atomicAdd(&accL[32 + oc], qq);
        }
    }
    __syncthreads();
    if (t < 32) {
        atomicAdd(&ws[SLOTS3  + t * 64 + slot], accL[t]);
        atomicAdd(&ws[SLOTS3Q + t * 64 + slot], accL[32 + t]);
    }
}

// ---------------------------------------------------------------------------
// K4: per-block BN3 finalize; out = x + bn3(o), nontemporal float4 stream.
__global__ __launch_bounds__(NT, 8)
void k4_w(const float* __restrict__ x, float* __restrict__ ws,
          const ushort* __restrict__ oi, float* __restrict__ out,
          const float* __restrict__ g3, const float* __restrict__ b3) {
    __shared__ float finL[64];
    dev_fin(ws, SLOTS3, SLOTS3Q, g3, b3, 32, 524288.0f, finL, threadIdx.x);
    #pragma unroll
    for (int it = 0; it < 8; it++) {
        size_t e = ((size_t)(it * 2048 + blockIdx.x) * 256 + threadIdx.x) * 4;
        int oc = (int)((e >> 16) & 31);
        float a3 = finL[oc], bb3 = finL[32 + oc];
        uint2 ov = *(const uint2*)(oi + e);
        float4 xv = *(const float4*)(x + e);
        f32x4n r;
        r.x = xv.x + bf16lo_to_f(ov.x) * a3 + bb3;
        r.y = xv.y + bf16hi_to_f(ov.x) * a3 + bb3;
        r.z = xv.z + bf16lo_to_f(ov.y) * a3 + bb3;
        r.w = xv.w + bf16hi_to_f(ov.y) * a3 + bb3;
        __builtin_nontemporal_store(r, (f32x4n*)(out + e));
    }
}

// ---------------------------------------------------------------------------
extern "C" void kernel_launch(void* const* d_in, const int* in_sizes, int n_in,
                              void* d_out, int out_size, void* d_ws, size_t ws_size,
                              hipStream_t stream) {
    const float* x  = (const float*)d_in[0];
    const float* s  = (const float*)d_in[1];
    const float* g1 = (const float*)d_in[2];
    const float* b1 = (const float*)d_in[3];
    const float* g2 = (const float*)d_in[4];
    const float* b2 = (const float*)d_in[5];
    const float* g3 = (const float*)d_in[6];
    const float* b3 = (const float*)d_in[7];
    float* out = (float*)d_out;
    float* ws  = (float*)d_ws;

    ushort* st2 = (ushort*)((char*)d_ws + ST2_OFF);
    ushort* zb  = (ushort*)((char*)d_ws + ZB_OFF);
    ushort* yb  = (ushort*)((char*)d_ws + Y_OFF);
    ushort* oi  = (ushort*)((char*)d_ws + OI_OFF);

    transpose_w1<<<8192, 256, 0, stream>>>(s, st2, ws);
    k1_w<<<6400, NT, 0, stream>>>(x, s, st2, yb, ws);
    k2_w<<<12288, NT, 0, stream>>>(yb, s, st2, zb, ws, g1, b1);
    k3_w<<<4096, NT, 0, stream>>>(zb, st2, oi, ws, g2, b2);
    k4_w<<<2048, NT, 0, stream>>>(x, ws, oi, out, g3, b3);
}